// Round 6
// baseline (488.580 us; speedup 1.0000x reference)
//
#include <hip/hip_runtime.h>
#include <math.h>

// Problem constants (P == D == 512).
static constexpr int PD = 512;
static constexpr float BASEV = 6.0f;
static constexpr int CAP = 320;   // slots per segment; counts ~150 +/- 12 => +14 sigma safe

typedef float f4v __attribute__((ext_vector_type(4)));
typedef int   i4v __attribute__((ext_vector_type(4)));
typedef int   i2v __attribute__((ext_vector_type(2)));

// ---------------------------------------------------------------------------
// Front kernel: fuses (a) attention logits and (b) edge binning.
// Edge fast path: for sorted unique neighbor ids, guess g = clamp(v - nb[0]);
// if nb[g]==v and (g==0 || nb[g-1]<v), g IS searchsorted-left(v) -- O(1).
// Binary-search fallback keeps generality.
// ---------------------------------------------------------------------------
__global__ __launch_bounds__(256) void front_kernel(
    const int* __restrict__ ei_f, const float* __restrict__ y_f,
    const int* __restrict__ ei_r, const float* __restrict__ y_r,
    const int* __restrict__ nb_f, const int* __restrict__ nb_r,
    const float* __restrict__ target, const float* __restrict__ formF,
    const float* __restrict__ roleF, const float* __restrict__ lemb,
    const float* __restrict__ W1, const float* __restrict__ b1,
    const float* __restrict__ W2, const float* __restrict__ b2,
    int N, int E, int AB, int EBf,
    int* __restrict__ cnt, int2* __restrict__ bins,
    float* __restrict__ logits) {
    __shared__ float sred[384];
    int b = blockIdx.x;
    if (b >= AB) {
        // ---- edge binning: 1024 edges per block, 4 per thread ----
        int b2 = b - AB;
        bool role = b2 >= EBf;
        const int* nb = role ? nb_r : nb_f;
        const int* ei = role ? ei_r : ei_f;
        const float* yy = role ? y_r : y_f;
        int base = (role ? b2 - EBf : b2) * 1024;
        int nb0 = nb[0];
#pragma unroll
        for (int r = 0; r < 4; r++) {
            int e = base + threadIdx.x + r * 256;
            if (e >= E) continue;
            int v = ei[e];
            int g = v - nb0; g = g < 0 ? 0 : (g >= N ? N - 1 : g);
            int pos;
            if (nb[g] == v && (g == 0 || nb[g - 1] < v)) {
                pos = g;                           // O(1) hit (shifted-identity table)
            } else {
                int lo = 0, hi = N;                // general fallback
                while (lo < hi) { int mid = (lo + hi) >> 1; if (nb[mid] < v) lo = mid + 1; else hi = mid; }
                pos = lo < N ? lo : N - 1;         // clip(ss, 0, N-1)
                if (nb[pos] != v) continue;        // invalid edge -> weight 0
            }
            int s = role ? N + pos : pos;
            float w = yy[e] - BASEV;
            int slot = atomicAdd(&cnt[s], 1);
            if (slot < CAP) {
                i2v val; val.x = ei[E + e]; val.y = __float_as_int(w);
                // NT: bins are streamed once downstream; keep them out of L2
                __builtin_nontemporal_store(val, reinterpret_cast<i2v*>(bins + (size_t)s * CAP + slot));
            }
        }
    } else {
        // ---- attention ----
        // Phase 1: block-wide constant term c_l[j] = b1[j] + target.W1 + lemb_l.W1
        float* spart = sred;                 // [4][64]
        float* sc0 = spart + 256;            // [64]
        float* sc1 = spart + 320;            // [64]
        int jj = threadIdx.x & 63, ck = threadIdx.x >> 6;
        const float* Wc = W1 + jj;
        float tp = 0.f;
        int p0 = ck * 128;
        for (int p = p0; p < p0 + 128; p += 4) {
            float4 tv = *(const float4*)(target + p);
            tp += tv.x * Wc[(size_t)(p + 0) * 64] + tv.y * Wc[(size_t)(p + 1) * 64]
                + tv.z * Wc[(size_t)(p + 2) * 64] + tv.w * Wc[(size_t)(p + 3) * 64];
        }
        spart[ck * 64 + jj] = tp;
        __syncthreads();
        if (ck == 0) {
            float c = b1[jj] + spart[jj] + spart[64 + jj] + spart[128 + jj] + spart[192 + jj];
            float c0 = c, c1 = c;
            for (int q = 0; q < 16; q++) {
                float wq = Wc[(size_t)(2 * PD + q) * 64];
                c0 += lemb[q] * wq;
                c1 += lemb[16 + q] * wq;
            }
            sc0[jj] = c0; sc1[jj] = c1;
        }
        __syncthreads();
        // Phase 2: one row per wave (4 rows/block).
        int wave = threadIdx.x >> 6, lane = threadIdx.x & 63;
        int rr = b * 4 + wave;
        int nseg = 2 * N;
        if (rr >= nseg) return;
        bool rl = rr >= N;
        const float* z = rl ? roleF + (size_t)(rr - N) * PD : formF + (size_t)rr * PD;
        const float* Wz = W1 + (size_t)PD * 64 + lane;
        float hA = rl ? sc1[lane] : sc0[lane];
        float hB = 0.f, hC = 0.f, hD = 0.f;
        for (int p = 0; p < PD; p += 8) {     // 4 independent FMA chains
            float4 z0 = *(const float4*)(z + p);
            float4 z1 = *(const float4*)(z + p + 4);
            hA += z0.x * Wz[(size_t)(p + 0) * 64] + z0.y * Wz[(size_t)(p + 1) * 64];
            hB += z0.z * Wz[(size_t)(p + 2) * 64] + z0.w * Wz[(size_t)(p + 3) * 64];
            hC += z1.x * Wz[(size_t)(p + 4) * 64] + z1.y * Wz[(size_t)(p + 5) * 64];
            hD += z1.z * Wz[(size_t)(p + 6) * 64] + z1.w * Wz[(size_t)(p + 7) * 64];
        }
        float hh = (hA + hB) + (hC + hD);
        hh = hh > 0.f ? hh : 0.2f * hh;       // LeakyReLU(0.2)
        float vv = hh * W2[lane];
#pragma unroll
        for (int off = 32; off > 0; off >>= 1) vv += __shfl_down(vv, off, 64);
        if (lane == 0) logits[rr] = vv + b2[0];
    }
}

// ---------------------------------------------------------------------------
// Column-sliced accumulate: block (slice s, segment g) computes
// msgs[g][128s : 128s+128] = sum_k w_k * drug[j_k][128s:128s+128].
// blockIdx.x = s + 4*g -> HW round-robin block->XCD mapping pins slice s to
// XCDs {s, s+4}: per-XCD hot drug footprint = 2000 rows x 512 B = 1 MB,
// comfortably L2-resident (was 4 MB = exactly L2 size -> capacity thrash).
// 64 threads: lanes = 2 entry-subsets x 32 col-lanes (float4 each).
// Extra block (b == 4*nseg) computes global softmax stats (m, Z) into sm[].
// ---------------------------------------------------------------------------
__global__ __launch_bounds__(64) void accum_kernel(const int* __restrict__ cnt,
                                                   const int2* __restrict__ bins,
                                                   const float* __restrict__ drug,
                                                   const float* __restrict__ logits,
                                                   int nseg,
                                                   float* __restrict__ sm,
                                                   float* __restrict__ msgs) {
    int b = blockIdx.x;
    int t = threadIdx.x;
    if (b == 4 * nseg) {
        // softmax stats over logits[0..nseg) -- one wave, shfl reduce
        float m = -1e30f;
        for (int s = t; s < nseg; s += 64) m = fmaxf(m, logits[s]);
#pragma unroll
        for (int o = 32; o > 0; o >>= 1) m = fmaxf(m, __shfl_xor(m, o, 64));
        float sum = 0.f;
        for (int s = t; s < nseg; s += 64) sum += expf(logits[s] - m);
#pragma unroll
        for (int o = 32; o > 0; o >>= 1) sum += __shfl_xor(sum, o, 64);
        if (t == 0) { sm[0] = m; sm[1] = sum; }
        return;
    }
    int slice = b & 3;
    int seg = b >> 2;
    int c0 = slice * 128;
    int n = cnt[seg]; n = n < CAP ? n : CAP;
    const int2* bb = bins + (size_t)seg * CAP;
    int sub = t >> 5, cl = t & 31;             // entry-subset, col-lane
    const float* dcol = drug + c0 + cl * 4;
    float4 acc = make_float4(0.f, 0.f, 0.f, 0.f);
    int k = 0;
    for (; k + 7 < n; k += 8) {                // 8 entries/iter: 4 per subset
        i2v e0 = __builtin_nontemporal_load(reinterpret_cast<const i2v*>(bb + k + 0 + sub));
        i2v e1 = __builtin_nontemporal_load(reinterpret_cast<const i2v*>(bb + k + 2 + sub));
        i2v e2 = __builtin_nontemporal_load(reinterpret_cast<const i2v*>(bb + k + 4 + sub));
        i2v e3 = __builtin_nontemporal_load(reinterpret_cast<const i2v*>(bb + k + 6 + sub));
        float4 d0 = *(const float4*)(dcol + (size_t)e0.x * PD);
        float4 d1 = *(const float4*)(dcol + (size_t)e1.x * PD);
        float4 d2 = *(const float4*)(dcol + (size_t)e2.x * PD);
        float4 d3 = *(const float4*)(dcol + (size_t)e3.x * PD);
        float w0 = __int_as_float(e0.y), w1 = __int_as_float(e1.y);
        float w2 = __int_as_float(e2.y), w3 = __int_as_float(e3.y);
        acc.x += w0 * d0.x; acc.y += w0 * d0.y; acc.z += w0 * d0.z; acc.w += w0 * d0.w;
        acc.x += w1 * d1.x; acc.y += w1 * d1.y; acc.z += w1 * d1.z; acc.w += w1 * d1.w;
        acc.x += w2 * d2.x; acc.y += w2 * d2.y; acc.z += w2 * d2.z; acc.w += w2 * d2.w;
        acc.x += w3 * d3.x; acc.y += w3 * d3.y; acc.z += w3 * d3.z; acc.w += w3 * d3.w;
    }
    for (; k < n; k++) {
        if (sub == 0) {
            int2 e0 = bb[k];
            float w0 = __int_as_float(e0.y);
            float4 d0 = *(const float4*)(dcol + (size_t)e0.x * PD);
            acc.x += w0 * d0.x; acc.y += w0 * d0.y; acc.z += w0 * d0.z; acc.w += w0 * d0.w;
        }
    }
    // combine the two entry-subsets (lane <-> lane+32)
    acc.x += __shfl_down(acc.x, 32, 64);
    acc.y += __shfl_down(acc.y, 32, 64);
    acc.z += __shfl_down(acc.z, 32, 64);
    acc.w += __shfl_down(acc.w, 32, 64);
    if (t < 32) {
        f4v av; av.x = acc.x; av.y = acc.y; av.z = acc.z; av.w = acc.w;
        __builtin_nontemporal_store(av,
            reinterpret_cast<f4v*>(msgs + (size_t)seg * PD + c0) + cl);
    }
}

// ---------------------------------------------------------------------------
// Weighted row sum -> v_prior, using precomputed softmax stats sm = {m, Z}.
// ---------------------------------------------------------------------------
__global__ __launch_bounds__(128) void vprior_kernel(const float* __restrict__ logits,
                                                     const float* __restrict__ msgs,
                                                     const float* __restrict__ sm,
                                                     int nseg, float* __restrict__ v_prior) {
    int t = threadIdx.x;
    float m = sm[0];
    float inv = 1.f / sm[1];
    float4 acc = make_float4(0.f, 0.f, 0.f, 0.f);
    for (int s = blockIdx.x; s < nseg; s += gridDim.x) {
        float w = expf(logits[s] - m) * inv;
        float4 d = ((const float4*)(msgs + (size_t)s * PD))[t];
        acc.x += w * d.x; acc.y += w * d.y; acc.z += w * d.z; acc.w += w * d.w;
    }
    atomicAdd(&v_prior[4 * t + 0], acc.x);
    atomicAdd(&v_prior[4 * t + 1], acc.y);
    atomicAdd(&v_prior[4 * t + 2], acc.z);
    atomicAdd(&v_prior[4 * t + 3], acc.w);
}

// ---------------------------------------------------------------------------
// h = v_prior @ Wi1 (partial over d-rows, atomic accumulate; bias+PReLU later)
// ---------------------------------------------------------------------------
__global__ __launch_bounds__(256) void mv1_kernel(const float* __restrict__ v_prior,
                                                  const float* __restrict__ Wi1,
                                                  float* __restrict__ h) {
    int b = blockIdx.x;    // 32 blocks x 16 rows
    int t = threadIdx.x;   // cols 2t, 2t+1
    float2 acc = make_float2(0.f, 0.f);
    int d0 = b * 16;
    for (int d = d0; d < d0 + 16; d++) {
        float vd = v_prior[d];
        float2 w = ((const float2*)(Wi1 + (size_t)d * PD))[t];
        acc.x += vd * w.x; acc.y += vd * w.y;
    }
    atomicAdd(&h[2 * t + 0], acc.x);
    atomicAdd(&h[2 * t + 1], acc.y);
}

// v = PReLU(h + bi1) @ Wi2 (partial over q-rows, atomic accumulate)
__global__ __launch_bounds__(256) void mv2_kernel(const float* __restrict__ h,
                                                  const float* __restrict__ bi1,
                                                  const float* __restrict__ alpha_p,
                                                  const float* __restrict__ Wi2,
                                                  float* __restrict__ v) {
    int b = blockIdx.x;
    int t = threadIdx.x;
    float alpha = alpha_p[0];
    float2 acc = make_float2(0.f, 0.f);
    int q0 = b * 16;
    for (int q = q0; q < q0 + 16; q++) {
        float hq = h[q] + bi1[q];
        hq = hq > 0.f ? hq : alpha * hq;
        float2 w = ((const float2*)(Wi2 + (size_t)q * PD))[t];
        acc.x += hq * w.x; acc.y += hq * w.y;
    }
    atomicAdd(&v[2 * t + 0], acc.x);
    atomicAdd(&v[2 * t + 1], acc.y);
}

// x = target + (v + bi2); LayerNorm -> z_refined (d_out[0:512])
__global__ __launch_bounds__(512) void final_kernel(const float* __restrict__ target,
                                                    const float* __restrict__ v,
                                                    const float* __restrict__ bi2,
                                                    const float* __restrict__ gamma,
                                                    const float* __restrict__ beta,
                                                    float* __restrict__ out) {
    __shared__ float red[512];
    int t = threadIdx.x;
    float x = target[t] + v[t] + bi2[t];
    red[t] = x; __syncthreads();
    for (int o = 256; o > 0; o >>= 1) { if (t < o) red[t] += red[t + o]; __syncthreads(); }
    float mu = red[0] * (1.f / 512.f);
    __syncthreads();
    float dx = x - mu;
    red[t] = dx * dx; __syncthreads();
    for (int o = 256; o > 0; o >>= 1) { if (t < o) red[t] += red[t + o]; __syncthreads(); }
    float var = red[0] * (1.f / 512.f);
    out[t] = dx * (1.f / sqrtf(var + 1e-5f)) * gamma[t] + beta[t];
}

// ---------------------------------------------------------------------------
extern "C" void kernel_launch(void* const* d_in, const int* in_sizes, int n_in,
                              void* d_out, int out_size, void* d_ws, size_t ws_size,
                              hipStream_t stream) {
    const float* target = (const float*)d_in[0];
    const float* formF  = (const float*)d_in[1];
    const float* roleF  = (const float*)d_in[2];
    const int*   nb_f   = (const int*)d_in[3];
    const int*   nb_r   = (const int*)d_in[4];
    const int*   ei_f   = (const int*)d_in[5];   // (2,E) flat: row0 src, row1 drug
    const float* y_f    = (const float*)d_in[6];
    const int*   ei_r   = (const int*)d_in[7];
    const float* y_r    = (const float*)d_in[8];
    const float* drug   = (const float*)d_in[9];
    const float* lemb   = (const float*)d_in[10];
    const float* W1     = (const float*)d_in[11];
    const float* b1     = (const float*)d_in[12];
    const float* W2     = (const float*)d_in[13];
    const float* b2     = (const float*)d_in[14];
    const float* Wi1    = (const float*)d_in[15];
    const float* bi1    = (const float*)d_in[16];
    const float* alpha  = (const float*)d_in[17];
    const float* Wi2    = (const float*)d_in[18];
    const float* bi2    = (const float*)d_in[19];
    const float* gamma  = (const float*)d_in[20];
    const float* beta   = (const float*)d_in[21];

    int N = in_sizes[3];
    int E = in_sizes[5] / 2;
    int nseg = 2 * N;

    // workspace layout (4-byte words)
    int* ws = (int*)d_ws;
    int*   cnt     = ws + 0;                 // 4096  (zeroed)
    float* v_prior = (float*)(ws + 4096);    // 512   (zeroed)
    float* hbuf    = (float*)(ws + 4608);    // 512   (zeroed)
    float* vbuf    = (float*)(ws + 5120);    // 512   (zeroed)
    float* logits  = (float*)(ws + 5632);    // 4096
    float* smbuf   = (float*)(ws + 9728);    // 2 (softmax stats m, Z)
    int2*  bins    = (int2*)(ws + 9736);     // 8B aligned; 4096*CAP int2

    float* out  = (float*)d_out;
    float* msgs = out + PD;   // [2N, 512] = form_msgs then role_msgs

    hipMemsetAsync(ws, 0, 5632 * sizeof(int), stream);  // cnt + v_prior + h + v

    int AB  = (nseg + 3) / 4;                // attention blocks: 4 waves x 1 row
    int EBf = (E + 1023) / 1024;             // edge blocks per layer (4 edges/thread)
    front_kernel<<<AB + 2 * EBf, 256, 0, stream>>>(ei_f, y_f, ei_r, y_r, nb_f, nb_r,
                                                   target, formF, roleF, lemb,
                                                   W1, b1, W2, b2, N, E, AB, EBf,
                                                   cnt, bins, logits);
    accum_kernel<<<4 * nseg + 1, 64, 0, stream>>>(cnt, bins, drug, logits, nseg, smbuf, msgs);
    vprior_kernel<<<256, 128, 0, stream>>>(logits, msgs, smbuf, nseg, v_prior);
    mv1_kernel<<<32, 256, 0, stream>>>(v_prior, Wi1, hbuf);
    mv2_kernel<<<32, 256, 0, stream>>>(hbuf, bi1, alpha, Wi2, vbuf);
    final_kernel<<<1, 512, 0, stream>>>(target, vbuf, bi2, gamma, beta, out);
}

// Round 7
// 443.064 us; speedup vs baseline: 1.1027x; 1.1027x over previous
//
#include <hip/hip_runtime.h>
#include <math.h>

// Problem constants (P == D == 512).
static constexpr int PD = 512;
static constexpr float BASEV = 6.0f;
static constexpr int CAP = 320;   // slots per segment; counts ~150 +/- 12 => +14 sigma safe

typedef float f4v __attribute__((ext_vector_type(4)));
typedef int   i4v __attribute__((ext_vector_type(4)));
typedef int   i2v __attribute__((ext_vector_type(2)));

// ---------------------------------------------------------------------------
// Front kernel: fuses (a) attention logits and (b) edge binning.
// Edge fast path: for sorted unique neighbor ids, guess g = clamp(v - nb[0]);
// if nb[g]==v and (g==0 || nb[g-1]<v), g IS searchsorted-left(v) -- O(1).
// Binary-search fallback keeps generality.
// ---------------------------------------------------------------------------
__global__ __launch_bounds__(256) void front_kernel(
    const int* __restrict__ ei_f, const float* __restrict__ y_f,
    const int* __restrict__ ei_r, const float* __restrict__ y_r,
    const int* __restrict__ nb_f, const int* __restrict__ nb_r,
    const float* __restrict__ target, const float* __restrict__ formF,
    const float* __restrict__ roleF, const float* __restrict__ lemb,
    const float* __restrict__ W1, const float* __restrict__ b1,
    const float* __restrict__ W2, const float* __restrict__ b2,
    int N, int E, int AB, int EBf,
    int* __restrict__ cnt, int2* __restrict__ bins,
    float* __restrict__ logits) {
    __shared__ float sred[384];
    int b = blockIdx.x;
    if (b >= AB) {
        // ---- edge binning: 1024 edges per block, 4 per thread ----
        int b2 = b - AB;
        bool role = b2 >= EBf;
        const int* nb = role ? nb_r : nb_f;
        const int* ei = role ? ei_r : ei_f;
        const float* yy = role ? y_r : y_f;
        int base = (role ? b2 - EBf : b2) * 1024;
        int nb0 = nb[0];
#pragma unroll
        for (int r = 0; r < 4; r++) {
            int e = base + threadIdx.x + r * 256;
            if (e >= E) continue;
            int v = ei[e];
            int g = v - nb0; g = g < 0 ? 0 : (g >= N ? N - 1 : g);
            int pos;
            if (nb[g] == v && (g == 0 || nb[g - 1] < v)) {
                pos = g;                           // O(1) hit (shifted-identity table)
            } else {
                int lo = 0, hi = N;                // general fallback
                while (lo < hi) { int mid = (lo + hi) >> 1; if (nb[mid] < v) lo = mid + 1; else hi = mid; }
                pos = lo < N ? lo : N - 1;         // clip(ss, 0, N-1)
                if (nb[pos] != v) continue;        // invalid edge -> weight 0
            }
            int s = role ? N + pos : pos;
            float w = yy[e] - BASEV;
            int slot = atomicAdd(&cnt[s], 1);
            if (slot < CAP) {
                i2v val; val.x = ei[E + e]; val.y = __float_as_int(w);
                // NT: bins are streamed once downstream; keep them out of L2
                __builtin_nontemporal_store(val, reinterpret_cast<i2v*>(bins + (size_t)s * CAP + slot));
            }
        }
    } else {
        // ---- attention ----
        // Phase 1: block-wide constant term c_l[j] = b1[j] + target.W1 + lemb_l.W1
        float* spart = sred;                 // [4][64]
        float* sc0 = spart + 256;            // [64]
        float* sc1 = spart + 320;            // [64]
        int jj = threadIdx.x & 63, ck = threadIdx.x >> 6;
        const float* Wc = W1 + jj;
        float tp = 0.f;
        int p0 = ck * 128;
        for (int p = p0; p < p0 + 128; p += 4) {
            float4 tv = *(const float4*)(target + p);
            tp += tv.x * Wc[(size_t)(p + 0) * 64] + tv.y * Wc[(size_t)(p + 1) * 64]
                + tv.z * Wc[(size_t)(p + 2) * 64] + tv.w * Wc[(size_t)(p + 3) * 64];
        }
        spart[ck * 64 + jj] = tp;
        __syncthreads();
        if (ck == 0) {
            float c = b1[jj] + spart[jj] + spart[64 + jj] + spart[128 + jj] + spart[192 + jj];
            float c0 = c, c1 = c;
            for (int q = 0; q < 16; q++) {
                float wq = Wc[(size_t)(2 * PD + q) * 64];
                c0 += lemb[q] * wq;
                c1 += lemb[16 + q] * wq;
            }
            sc0[jj] = c0; sc1[jj] = c1;
        }
        __syncthreads();
        // Phase 2: one row per wave (4 rows/block).
        int wave = threadIdx.x >> 6, lane = threadIdx.x & 63;
        int rr = b * 4 + wave;
        int nseg = 2 * N;
        if (rr >= nseg) return;
        bool rl = rr >= N;
        const float* z = rl ? roleF + (size_t)(rr - N) * PD : formF + (size_t)rr * PD;
        const float* Wz = W1 + (size_t)PD * 64 + lane;
        float hA = rl ? sc1[lane] : sc0[lane];
        float hB = 0.f, hC = 0.f, hD = 0.f;
        for (int p = 0; p < PD; p += 8) {     // 4 independent FMA chains
            float4 z0 = *(const float4*)(z + p);
            float4 z1 = *(const float4*)(z + p + 4);
            hA += z0.x * Wz[(size_t)(p + 0) * 64] + z0.y * Wz[(size_t)(p + 1) * 64];
            hB += z0.z * Wz[(size_t)(p + 2) * 64] + z0.w * Wz[(size_t)(p + 3) * 64];
            hC += z1.x * Wz[(size_t)(p + 4) * 64] + z1.y * Wz[(size_t)(p + 5) * 64];
            hD += z1.z * Wz[(size_t)(p + 6) * 64] + z1.w * Wz[(size_t)(p + 7) * 64];
        }
        float hh = (hA + hB) + (hC + hD);
        hh = hh > 0.f ? hh : 0.2f * hh;       // LeakyReLU(0.2)
        float vv = hh * W2[lane];
#pragma unroll
        for (int off = 32; off > 0; off >>= 1) vv += __shfl_down(vv, off, 64);
        if (lane == 0) logits[rr] = vv + b2[0];
    }
}

// ---------------------------------------------------------------------------
// Accumulate sum_k w_k * drug[j_k] per segment. One block (128 thr) per
// segment; float4 per thread covers 512 cols; SIXTEEN independent row loads
// in flight (gather is L2-latency-bound; deeper MLP -> closer to L2-BW
// floor). NT bins loads + NT msgs stores keep the 4 MB drug table hot.
// Extra block (b == nseg) computes global softmax stats (m, Z) into sm[].
// ---------------------------------------------------------------------------
__global__ __launch_bounds__(128) void accum_kernel(const int* __restrict__ cnt,
                                                    const int2* __restrict__ bins,
                                                    const float* __restrict__ drug,
                                                    const float* __restrict__ logits,
                                                    int nseg,
                                                    float* __restrict__ sm,
                                                    float* __restrict__ msgs) {
    int b = blockIdx.x;
    int t = threadIdx.x;
    if (b == nseg) {
        // softmax stats over logits[0..nseg)
        __shared__ float red[128];
        float m = -1e30f;
        for (int s = t; s < nseg; s += 128) m = fmaxf(m, logits[s]);
        red[t] = m; __syncthreads();
        for (int o = 64; o > 0; o >>= 1) { if (t < o) red[t] = fmaxf(red[t], red[t + o]); __syncthreads(); }
        m = red[0]; __syncthreads();
        float sum = 0.f;
        for (int s = t; s < nseg; s += 128) sum += expf(logits[s] - m);
        red[t] = sum; __syncthreads();
        for (int o = 64; o > 0; o >>= 1) { if (t < o) red[t] += red[t + o]; __syncthreads(); }
        if (t == 0) { sm[0] = m; sm[1] = red[0]; }
        return;
    }
    int n = cnt[b]; n = n < CAP ? n : CAP;
    const int2* bb = bins + (size_t)b * CAP;
    float4 acc = make_float4(0.f, 0.f, 0.f, 0.f);
    int k = 0;
    for (; k + 15 < n; k += 16) {
        i4v q0 = __builtin_nontemporal_load(reinterpret_cast<const i4v*>(bb + k + 0));
        i4v q1 = __builtin_nontemporal_load(reinterpret_cast<const i4v*>(bb + k + 2));
        i4v q2 = __builtin_nontemporal_load(reinterpret_cast<const i4v*>(bb + k + 4));
        i4v q3 = __builtin_nontemporal_load(reinterpret_cast<const i4v*>(bb + k + 6));
        i4v q4 = __builtin_nontemporal_load(reinterpret_cast<const i4v*>(bb + k + 8));
        i4v q5 = __builtin_nontemporal_load(reinterpret_cast<const i4v*>(bb + k + 10));
        i4v q6 = __builtin_nontemporal_load(reinterpret_cast<const i4v*>(bb + k + 12));
        i4v q7 = __builtin_nontemporal_load(reinterpret_cast<const i4v*>(bb + k + 14));
        float4 d0 = ((const float4*)(drug + (size_t)q0.x * PD))[t];
        float4 d1 = ((const float4*)(drug + (size_t)q0.z * PD))[t];
        float4 d2 = ((const float4*)(drug + (size_t)q1.x * PD))[t];
        float4 d3 = ((const float4*)(drug + (size_t)q1.z * PD))[t];
        float4 d4 = ((const float4*)(drug + (size_t)q2.x * PD))[t];
        float4 d5 = ((const float4*)(drug + (size_t)q2.z * PD))[t];
        float4 d6 = ((const float4*)(drug + (size_t)q3.x * PD))[t];
        float4 d7 = ((const float4*)(drug + (size_t)q3.z * PD))[t];
        float4 d8 = ((const float4*)(drug + (size_t)q4.x * PD))[t];
        float4 d9 = ((const float4*)(drug + (size_t)q4.z * PD))[t];
        float4 da = ((const float4*)(drug + (size_t)q5.x * PD))[t];
        float4 db = ((const float4*)(drug + (size_t)q5.z * PD))[t];
        float4 dc = ((const float4*)(drug + (size_t)q6.x * PD))[t];
        float4 dd = ((const float4*)(drug + (size_t)q6.z * PD))[t];
        float4 de = ((const float4*)(drug + (size_t)q7.x * PD))[t];
        float4 df = ((const float4*)(drug + (size_t)q7.z * PD))[t];
        float w0 = __int_as_float(q0.y), w1 = __int_as_float(q0.w);
        float w2 = __int_as_float(q1.y), w3 = __int_as_float(q1.w);
        float w4 = __int_as_float(q2.y), w5 = __int_as_float(q2.w);
        float w6 = __int_as_float(q3.y), w7 = __int_as_float(q3.w);
        float w8 = __int_as_float(q4.y), w9 = __int_as_float(q4.w);
        float wa = __int_as_float(q5.y), wb = __int_as_float(q5.w);
        float wc = __int_as_float(q6.y), wd = __int_as_float(q6.w);
        float we = __int_as_float(q7.y), wf = __int_as_float(q7.w);
        acc.x += w0 * d0.x; acc.y += w0 * d0.y; acc.z += w0 * d0.z; acc.w += w0 * d0.w;
        acc.x += w1 * d1.x; acc.y += w1 * d1.y; acc.z += w1 * d1.z; acc.w += w1 * d1.w;
        acc.x += w2 * d2.x; acc.y += w2 * d2.y; acc.z += w2 * d2.z; acc.w += w2 * d2.w;
        acc.x += w3 * d3.x; acc.y += w3 * d3.y; acc.z += w3 * d3.z; acc.w += w3 * d3.w;
        acc.x += w4 * d4.x; acc.y += w4 * d4.y; acc.z += w4 * d4.z; acc.w += w4 * d4.w;
        acc.x += w5 * d5.x; acc.y += w5 * d5.y; acc.z += w5 * d5.z; acc.w += w5 * d5.w;
        acc.x += w6 * d6.x; acc.y += w6 * d6.y; acc.z += w6 * d6.z; acc.w += w6 * d6.w;
        acc.x += w7 * d7.x; acc.y += w7 * d7.y; acc.z += w7 * d7.z; acc.w += w7 * d7.w;
        acc.x += w8 * d8.x; acc.y += w8 * d8.y; acc.z += w8 * d8.z; acc.w += w8 * d8.w;
        acc.x += w9 * d9.x; acc.y += w9 * d9.y; acc.z += w9 * d9.z; acc.w += w9 * d9.w;
        acc.x += wa * da.x; acc.y += wa * da.y; acc.z += wa * da.z; acc.w += wa * da.w;
        acc.x += wb * db.x; acc.y += wb * db.y; acc.z += wb * db.z; acc.w += wb * db.w;
        acc.x += wc * dc.x; acc.y += wc * dc.y; acc.z += wc * dc.z; acc.w += wc * dc.w;
        acc.x += wd * dd.x; acc.y += wd * dd.y; acc.z += wd * dd.z; acc.w += wd * dd.w;
        acc.x += we * de.x; acc.y += we * de.y; acc.z += we * de.z; acc.w += we * de.w;
        acc.x += wf * df.x; acc.y += wf * df.y; acc.z += wf * df.z; acc.w += wf * df.w;
    }
    for (; k + 3 < n; k += 4) {
        i4v q0 = __builtin_nontemporal_load(reinterpret_cast<const i4v*>(bb + k + 0));
        i4v q1 = __builtin_nontemporal_load(reinterpret_cast<const i4v*>(bb + k + 2));
        float4 d0 = ((const float4*)(drug + (size_t)q0.x * PD))[t];
        float4 d1 = ((const float4*)(drug + (size_t)q0.z * PD))[t];
        float4 d2 = ((const float4*)(drug + (size_t)q1.x * PD))[t];
        float4 d3 = ((const float4*)(drug + (size_t)q1.z * PD))[t];
        float w0 = __int_as_float(q0.y), w1 = __int_as_float(q0.w);
        float w2 = __int_as_float(q1.y), w3 = __int_as_float(q1.w);
        acc.x += w0 * d0.x; acc.y += w0 * d0.y; acc.z += w0 * d0.z; acc.w += w0 * d0.w;
        acc.x += w1 * d1.x; acc.y += w1 * d1.y; acc.z += w1 * d1.z; acc.w += w1 * d1.w;
        acc.x += w2 * d2.x; acc.y += w2 * d2.y; acc.z += w2 * d2.z; acc.w += w2 * d2.w;
        acc.x += w3 * d3.x; acc.y += w3 * d3.y; acc.z += w3 * d3.z; acc.w += w3 * d3.w;
    }
    for (; k < n; k++) {
        int2 e0 = bb[k];
        float w0 = __int_as_float(e0.y);
        float4 d0 = ((const float4*)(drug + (size_t)e0.x * PD))[t];
        acc.x += w0 * d0.x; acc.y += w0 * d0.y; acc.z += w0 * d0.z; acc.w += w0 * d0.w;
    }
    f4v av; av.x = acc.x; av.y = acc.y; av.z = acc.z; av.w = acc.w;
    __builtin_nontemporal_store(av, reinterpret_cast<f4v*>(msgs + (size_t)b * PD) + t);
}

// ---------------------------------------------------------------------------
// Weighted row sum -> v_prior, using precomputed softmax stats sm = {m, Z}.
// ---------------------------------------------------------------------------
__global__ __launch_bounds__(128) void vprior_kernel(const float* __restrict__ logits,
                                                     const float* __restrict__ msgs,
                                                     const float* __restrict__ sm,
                                                     int nseg, float* __restrict__ v_prior) {
    int t = threadIdx.x;
    float m = sm[0];
    float inv = 1.f / sm[1];
    float4 acc = make_float4(0.f, 0.f, 0.f, 0.f);
    for (int s = blockIdx.x; s < nseg; s += gridDim.x) {
        float w = expf(logits[s] - m) * inv;
        float4 d = ((const float4*)(msgs + (size_t)s * PD))[t];
        acc.x += w * d.x; acc.y += w * d.y; acc.z += w * d.z; acc.w += w * d.w;
    }
    atomicAdd(&v_prior[4 * t + 0], acc.x);
    atomicAdd(&v_prior[4 * t + 1], acc.y);
    atomicAdd(&v_prior[4 * t + 2], acc.z);
    atomicAdd(&v_prior[4 * t + 3], acc.w);
}

// ---------------------------------------------------------------------------
// h = v_prior @ Wi1 (partial over d-rows, atomic accumulate; bias+PReLU later)
// ---------------------------------------------------------------------------
__global__ __launch_bounds__(256) void mv1_kernel(const float* __restrict__ v_prior,
                                                  const float* __restrict__ Wi1,
                                                  float* __restrict__ h) {
    int b = blockIdx.x;    // 32 blocks x 16 rows
    int t = threadIdx.x;   // cols 2t, 2t+1
    float2 acc = make_float2(0.f, 0.f);
    int d0 = b * 16;
    for (int d = d0; d < d0 + 16; d++) {
        float vd = v_prior[d];
        float2 w = ((const float2*)(Wi1 + (size_t)d * PD))[t];
        acc.x += vd * w.x; acc.y += vd * w.y;
    }
    atomicAdd(&h[2 * t + 0], acc.x);
    atomicAdd(&h[2 * t + 1], acc.y);
}

// v = PReLU(h + bi1) @ Wi2 (partial over q-rows, atomic accumulate)
__global__ __launch_bounds__(256) void mv2_kernel(const float* __restrict__ h,
                                                  const float* __restrict__ bi1,
                                                  const float* __restrict__ alpha_p,
                                                  const float* __restrict__ Wi2,
                                                  float* __restrict__ v) {
    int b = blockIdx.x;
    int t = threadIdx.x;
    float alpha = alpha_p[0];
    float2 acc = make_float2(0.f, 0.f);
    int q0 = b * 16;
    for (int q = q0; q < q0 + 16; q++) {
        float hq = h[q] + bi1[q];
        hq = hq > 0.f ? hq : alpha * hq;
        float2 w = ((const float2*)(Wi2 + (size_t)q * PD))[t];
        acc.x += hq * w.x; acc.y += hq * w.y;
    }
    atomicAdd(&v[2 * t + 0], acc.x);
    atomicAdd(&v[2 * t + 1], acc.y);
}

// x = target + (v + bi2); LayerNorm -> z_refined (d_out[0:512])
__global__ __launch_bounds__(512) void final_kernel(const float* __restrict__ target,
                                                    const float* __restrict__ v,
                                                    const float* __restrict__ bi2,
                                                    const float* __restrict__ gamma,
                                                    const float* __restrict__ beta,
                                                    float* __restrict__ out) {
    __shared__ float red[512];
    int t = threadIdx.x;
    float x = target[t] + v[t] + bi2[t];
    red[t] = x; __syncthreads();
    for (int o = 256; o > 0; o >>= 1) { if (t < o) red[t] += red[t + o]; __syncthreads(); }
    float mu = red[0] * (1.f / 512.f);
    __syncthreads();
    float dx = x - mu;
    red[t] = dx * dx; __syncthreads();
    for (int o = 256; o > 0; o >>= 1) { if (t < o) red[t] += red[t + o]; __syncthreads(); }
    float var = red[0] * (1.f / 512.f);
    out[t] = dx * (1.f / sqrtf(var + 1e-5f)) * gamma[t] + beta[t];
}

// ---------------------------------------------------------------------------
extern "C" void kernel_launch(void* const* d_in, const int* in_sizes, int n_in,
                              void* d_out, int out_size, void* d_ws, size_t ws_size,
                              hipStream_t stream) {
    const float* target = (const float*)d_in[0];
    const float* formF  = (const float*)d_in[1];
    const float* roleF  = (const float*)d_in[2];
    const int*   nb_f   = (const int*)d_in[3];
    const int*   nb_r   = (const int*)d_in[4];
    const int*   ei_f   = (const int*)d_in[5];   // (2,E) flat: row0 src, row1 drug
    const float* y_f    = (const float*)d_in[6];
    const int*   ei_r   = (const int*)d_in[7];
    const float* y_r    = (const float*)d_in[8];
    const float* drug   = (const float*)d_in[9];
    const float* lemb   = (const float*)d_in[10];
    const float* W1     = (const float*)d_in[11];
    const float* b1     = (const float*)d_in[12];
    const float* W2     = (const float*)d_in[13];
    const float* b2     = (const float*)d_in[14];
    const float* Wi1    = (const float*)d_in[15];
    const float* bi1    = (const float*)d_in[16];
    const float* alpha  = (const float*)d_in[17];
    const float* Wi2    = (const float*)d_in[18];
    const float* bi2    = (const float*)d_in[19];
    const float* gamma  = (const float*)d_in[20];
    const float* beta   = (const float*)d_in[21];

    int N = in_sizes[3];
    int E = in_sizes[5] / 2;
    int nseg = 2 * N;

    // workspace layout (4-byte words)
    int* ws = (int*)d_ws;
    int*   cnt     = ws + 0;                 // 4096  (zeroed)
    float* v_prior = (float*)(ws + 4096);    // 512   (zeroed)
    float* hbuf    = (float*)(ws + 4608);    // 512   (zeroed)
    float* vbuf    = (float*)(ws + 5120);    // 512   (zeroed)
    float* logits  = (float*)(ws + 5632);    // 4096
    float* smbuf   = (float*)(ws + 9728);    // 2 (softmax stats m, Z)
    int2*  bins    = (int2*)(ws + 9736);     // 8B aligned; 4096*CAP int2

    float* out  = (float*)d_out;
    float* msgs = out + PD;   // [2N, 512] = form_msgs then role_msgs

    hipMemsetAsync(ws, 0, 5632 * sizeof(int), stream);  // cnt + v_prior + h + v

    int AB  = (nseg + 3) / 4;                // attention blocks: 4 waves x 1 row
    int EBf = (E + 1023) / 1024;             // edge blocks per layer (4 edges/thread)
    front_kernel<<<AB + 2 * EBf, 256, 0, stream>>>(ei_f, y_f, ei_r, y_r, nb_f, nb_r,
                                                   target, formF, roleF, lemb,
                                                   W1, b1, W2, b2, N, E, AB, EBf,
                                                   cnt, bins, logits);
    accum_kernel<<<nseg + 1, 128, 0, stream>>>(cnt, bins, drug, logits, nseg, smbuf, msgs);
    vprior_kernel<<<256, 128, 0, stream>>>(logits, msgs, smbuf, nseg, v_prior);
    mv1_kernel<<<32, 256, 0, stream>>>(v_prior, Wi1, hbuf);
    mv2_kernel<<<32, 256, 0, stream>>>(hbuf, bi1, alpha, Wi2, vbuf);
    final_kernel<<<1, 512, 0, stream>>>(target, vbuf, bi2, gamma, beta, out);
}